// Round 6
// baseline (167.665 us; speedup 1.0000x reference)
//
#include <hip/hip_runtime.h>
#include <cstdint>

#define HDIM 256
#define MT   256      // feature rows per block (4 waves x 64 rows)
#define BD   32       // En rows per K-loop iteration
#define SPLITS 32
#define RPB  16       // rows per prep block (4 per wave)

typedef short bf16x8 __attribute__((ext_vector_type(8)));
typedef short bf16x4 __attribute__((ext_vector_type(4)));
typedef float f32x4  __attribute__((ext_vector_type(4)));

typedef const __attribute__((address_space(1))) short as1_short;
typedef __attribute__((address_space(3))) short as3_short;

static __device__ __forceinline__ short f2bf(float x) {
    union { float f; uint32_t u; } v; v.f = x;
    uint32_t u = v.u;
    uint32_t r = (u + 0x7fffu + ((u >> 16) & 1u)) >> 16;
    return (short)r;
}

// ---- prep (single dispatch):
//  blocks [0, nb_nrm)          : L2-normalize feature/ex_feature rows -> bf16,
//                                stored with XOR-16B-chunk swizzle. r15: 4 rows
//                                per wave (16/block) — old 4KB-per-block grid
//                                was latency/launch-ramp bound, ~50us for a
//                                32MB-traffic job.
//  blocks [nb_nrm, nb_nrm+128) : transpose class reps to Rt[32][D] (col C = 1.0
//                                -> intensity falls out of the echo GEMM)
__global__ __launch_bounds__(256) void prep_kernel(const float* __restrict__ fsrc,
                                                   const float* __restrict__ esrc,
                                                   const float* __restrict__ reps,
                                                   short* __restrict__ dst,
                                                   short* __restrict__ rt,
                                                   int N, int rows_total,
                                                   int D, int C, int nb_nrm) {
    __shared__ float lds[128][29];                    // +1 pad col
    const int tid = threadIdx.x;
    if ((int)blockIdx.x < nb_nrm) {
        int wv = tid >> 6;
        int lane = tid & 63;
        int row0 = blockIdx.x * RPB + wv * 4;
        #pragma unroll
        for (int rr = 0; rr < 4; ++rr) {
            int row = row0 + rr;
            if (row >= rows_total) continue;
            const float* src = (row < N) ? (fsrc + (size_t)row * HDIM)
                                         : (esrc + (size_t)(row - N) * HDIM);
            const float4 v = *(const float4*)(src + lane * 4);
            float ss = v.x * v.x + v.y * v.y + v.z * v.z + v.w * v.w;
            #pragma unroll
            for (int m = 1; m < 64; m <<= 1) ss += __shfl_xor(ss, m, 64);
            float scale = 1.0f / fmaxf(sqrtf(ss), 1e-12f);
            short4 o;
            o.x = f2bf(v.x * scale); o.y = f2bf(v.y * scale);
            o.z = f2bf(v.z * scale); o.w = f2bf(v.w * scale);
            int chunk = (lane >> 1) ^ (row & 7);      // swizzled 16B-chunk index
            *(short4*)(dst + (size_t)row * HDIM + chunk * 8 + (lane & 1) * 4) = o;
        }
    } else {
        const int bx = blockIdx.x - nb_nrm;           // 0..127
        const int d0 = bx * 128;
        const int total = 128 * C;
        const float* src = reps + (size_t)d0 * C;
        for (int i = tid; i < total; i += 256)
            lds[i / C][i % C] = src[i];               // coalesced load
        __syncthreads();
        const int c = tid >> 3;                       // 0..31
        const int dsub = (tid & 7) * 16;              // 16 d per thread
        short* dstp = rt + (size_t)c * D + d0 + dsub;
        #pragma unroll
        for (int j0 = 0; j0 < 16; j0 += 4) {
            short4 o;
            float v0, v1, v2, v3;
            if (c < C) {
                v0 = lds[dsub + j0 + 0][c]; v1 = lds[dsub + j0 + 1][c];
                v2 = lds[dsub + j0 + 2][c]; v3 = lds[dsub + j0 + 3][c];
            } else {
                float f = (c == C) ? 1.0f : 0.0f;     // ones column -> intensity
                v0 = v1 = v2 = v3 = f;
            }
            o.x = f2bf(v0); o.y = f2bf(v1); o.z = f2bf(v2); o.w = f2bf(v3);
            *(short4*)(dstp + j0) = o;                // coalesced store
        }
    }
}

// ---- fused: GEMM1 computes S^T via operand-swapped MFMA (A=En, B=Fn), so the
// activated tile sits in 16x16x16 B-operand layout and feeds GEMM2
// echo^T += Rt_frag * a^T with NO LDS round-trip. En staged via global_load_lds
// double buffer. XOR de-swizzle stays in per-lane addresses.
//
// SESSION LEDGER:
//  r9  T15 @128-reg cap      -> spill (FETCH 18->139MB). Cap artifact, not T15.
//  r10 asm cvt_pk            -> reg-pinning spill. DEAD.
//  r11 no-LDS direct-global  -> VMEM issue-bound (16 lines/load). DEAD.
//  r13 atomic epilogue       -> cross-XCD fabric traffic, WRITE 26->97MB. DEAD.
//  r14 MT=256 @(256,2)       -> LDS/FETCH/conflicts halved ✓, wall FLAT:
//      occupancy 35->20% stripped the latency hiding; ~37% of window is now
//      dependency stall (serial GEMM1-end -> act -> GEMM2 -> barrier tail).
// r16 (this): T15 deferral REAPPLIED at the 256-reg budget where it fits:
// GEMM1(cur) co-scheduled with act+GEMM2(prev). Peak live = afrag 128 +
// echo 32 + sT_prev 32 + sT_cur 32 + temps ~= 240 < 256. Static sTa/sTb
// ping-pong, loop unrolled by 2 (rule 20). Barrier scheme unchanged from r8.
__global__ __launch_bounds__(256, 2) void fused_kernel(const short* __restrict__ Fn,
                                                       const short* __restrict__ En,
                                                       const short* __restrict__ Rt,
                                                       const int* __restrict__ pptr,
                                                       float* __restrict__ partial,
                                                       int N, int D, int C, int Dchunk) {
    __shared__ __align__(16) short lds_en[2][BD * HDIM];   // 2 x 16 KB double buffer

    const int tid  = threadIdx.x;
    const int lane = tid & 63;
    const int wv   = tid >> 6;
    const int q    = lane >> 4;
    const int l    = lane & 15;
    const int p    = pptr[0];

    const int Mbase = blockIdx.y * MT;
    const int dbase = blockIdx.x * Dchunk;

    const f32x4 zf = {0.0f, 0.0f, 0.0f, 0.0f};

    // Fn fragments (B-operand of GEMM1): B[k=ks*32+q*8+j][n=l] — de-swizzle in
    // the address. 4 f-tiles x 8 ks = 128 VGPR, resident for the whole kernel.
    bf16x8 afrag[4][8];
    #pragma unroll
    for (int fn = 0; fn < 4; ++fn) {
        const short* rowp = Fn + (size_t)(Mbase + wv * 64 + fn * 16 + l) * HDIM;
        #pragma unroll
        for (int ks = 0; ks < 8; ++ks)
            afrag[fn][ks] = *(const bf16x8*)(rowp + (((ks * 4 + q) ^ (l & 7)) << 3));
    }

    // echo^T accumulators: [f-tile][c-tile], C/D layout col=f(l), row=c(q*4+r)
    f32x4 echo_acc[4][2];
    #pragma unroll
    for (int fn = 0; fn < 4; ++fn) { echo_acc[fn][0] = zf; echo_acc[fn][1] = zf; }

    const int iters = Dchunk / BD;       // 16: even, >= 4

    #define STAGE(buf_, it_)                                                        \
        {                                                                           \
            const short* gbase = En + (size_t)(dbase + (it_) * BD) * HDIM + tid * 8;\
            _Pragma("unroll")                                                       \
            for (int i = 0; i < 4; ++i) {                                           \
                as3_short* lp = (as3_short*)(lds_en[buf_] + (i * 256 + wv * 64) * 8);\
                __builtin_amdgcn_global_load_lds((as1_short*)(gbase + i * 2048),    \
                                                 lp, 16, 0, 0);                     \
            }                                                                       \
        }

    // GEMM1: S^T tiles [en][fn], 32(D) x 64(M) per wave, K=256.
    #define GEMM1(BUF_, ST_)                                                        \
        {                                                                           \
            _Pragma("unroll")                                                       \
            for (int en = 0; en < 2; ++en)                                          \
                _Pragma("unroll")                                                   \
                for (int fn = 0; fn < 4; ++fn) ST_[en][fn] = zf;                    \
            _Pragma("unroll")                                                       \
            for (int ks = 0; ks < 8; ++ks) {                                        \
                _Pragma("unroll")                                                   \
                for (int en = 0; en < 2; ++en) {                                    \
                    const int row  = en * 16 + l;                                   \
                    const int slot = (ks * 4 + q) ^ (l & 7);                        \
                    bf16x8 ef = *(const bf16x8*)(lds_en[BUF_] + row * HDIM + slot * 8); \
                    _Pragma("unroll")                                               \
                    for (int fn = 0; fn < 4; ++fn)                                  \
                        ST_[en][fn] = __builtin_amdgcn_mfma_f32_16x16x32_bf16(ef, afrag[fn][ks], ST_[en][fn], 0, 0, 0); \
                }                                                                   \
            }                                                                       \
        }

    // Deferred tail for iteration IT_ (S^T in ST_): rt loads first (L2 latency
    // hides under act VALU), then activation -> packed bf16, then GEMM2.
    #define ACT2(ST_, IT_)                                                          \
        {                                                                           \
            const int d0p = dbase + (IT_) * BD;                                     \
            bf16x4 rt_f[2][2];                                                      \
            _Pragma("unroll")                                                       \
            for (int dblk = 0; dblk < 2; ++dblk) {                                  \
                const int doff = d0p + dblk * 16;                                   \
                rt_f[dblk][0] = *(const bf16x4*)(rtp + doff);                       \
                rt_f[dblk][1] = *(const bf16x4*)(rtp + (size_t)16 * D + doff);      \
            }                                                                       \
            bf16x4 pfrag[4][2];                                                     \
            _Pragma("unroll")                                                       \
            for (int en = 0; en < 2; ++en) {                                        \
                _Pragma("unroll")                                                   \
                for (int fn = 0; fn < 4; ++fn) {                                    \
                    bf16x4 pf;                                                      \
                    _Pragma("unroll")                                               \
                    for (int r = 0; r < 4; ++r) {                                   \
                        float sv = ST_[en][fn][r];                                  \
                        float a;                                                    \
                        if (p == 3)      a = sv * sv * sv;                          \
                        else if (p == 1) a = sv;                                    \
                        else if (p == 2) a = sv * fabsf(sv);                        \
                        else             a = copysignf(powf(fabsf(sv), (float)p), sv); \
                        pf[r] = f2bf(a);                                            \
                    }                                                               \
                    pfrag[fn][en] = pf;                                             \
                }                                                                   \
            }                                                                       \
            _Pragma("unroll")                                                       \
            for (int dblk = 0; dblk < 2; ++dblk) {                                  \
                _Pragma("unroll")                                                   \
                for (int fn = 0; fn < 4; ++fn) {                                    \
                    echo_acc[fn][0] = __builtin_amdgcn_mfma_f32_16x16x16bf16_1k(rt_f[dblk][0], pfrag[fn][dblk], echo_acc[fn][0], 0, 0, 0); \
                    echo_acc[fn][1] = __builtin_amdgcn_mfma_f32_16x16x16bf16_1k(rt_f[dblk][1], pfrag[fn][dblk], echo_acc[fn][1], 0, 0, 0); \
                }                                                                   \
            }                                                                       \
        }

    const short* rtp = Rt + (size_t)l * D + q * 4;    // c-tile 0 row; +16*D for tile 1

    f32x4 sTa[2][4];
    f32x4 sTb[2][4];

    // ---- prologue ----
    STAGE(0, 0)
    __syncthreads();                  // stage(0) landed
    STAGE(1, 1)
    GEMM1(0, sTa)

    __syncthreads();                  // stage(1) landed; buf0 reads done
    STAGE(0, 2)
    GEMM1(1, sTb)
    ACT2(sTa, 0)

    // ---- steady state: tile t lives in buf t&1; stage(t) issued at t-2 ----
    for (int it = 2; it < iters; it += 2) {
        __syncthreads();              // stage(it) landed; buf0 reads done
        if (it + 1 < iters) STAGE(1, it + 1)
        GEMM1(0, sTa)
        ACT2(sTb, it - 1)

        __syncthreads();              // stage(it+1) landed; buf1 reads done
        if (it + 2 < iters) STAGE(0, it + 2)
        GEMM1(1, sTb)
        ACT2(sTa, it)
    }
    ACT2(sTb, iters - 1)              // iters even -> last tile is in sTb

    // Epilogue: echo^T C-layout (col f = l, rows c = ct*16 + q*4 + r) -> one
    // float4 store per (f-tile, c-tile); reduce kernel ignores c > C.
    #pragma unroll
    for (int fn = 0; fn < 4; ++fn) {
        const int grow = Mbase + wv * 64 + fn * 16 + l;
        float* rowp = partial + ((size_t)blockIdx.x * N + grow) * 32 + q * 4;
        *(f32x4*)(rowp)      = echo_acc[fn][0];
        *(f32x4*)(rowp + 16) = echo_acc[fn][1];
    }

    #undef STAGE
    #undef GEMM1
    #undef ACT2
}

// ---- reduce: sum partials over splits; col<C -> echo, col==C -> intensity ----
__global__ __launch_bounds__(256) void reduce_kernel(const float* __restrict__ partial,
                                                     float* __restrict__ echo,
                                                     float* __restrict__ inten,
                                                     int N, int splits, int C) {
    int t = blockIdx.x * 256 + threadIdx.x;    // N*32 threads
    int row = t >> 5, c = t & 31;
    if (row >= N || c > C) return;
    float s = 0.0f;
    for (int k = 0; k < splits; ++k)
        s += partial[((size_t)k * N + (size_t)row) * 32 + c];
    if (c < C) echo[(size_t)row * C + c] = s;
    else       inten[row] = s;
}

extern "C" void kernel_launch(void* const* d_in, const int* in_sizes, int n_in,
                              void* d_out, int out_size, void* d_ws, size_t ws_size,
                              hipStream_t stream) {
    const int N = in_sizes[0] / HDIM;       // 4096
    const int D = in_sizes[1] / HDIM;       // 16384
    const int C = in_sizes[2] / D;          // 28

    const float* feat = (const float*)d_in[0];
    const float* exf  = (const float*)d_in[1];
    const float* reps = (const float*)d_in[2];
    const int*   p    = (const int*)d_in[3];

    short* Fn = (short*)d_ws;                          // [N][256] bf16 (swizzled)
    short* En = Fn + (size_t)N * HDIM;                 // [D][256] bf16 (swizzled)
    short* Rt = En + (size_t)D * HDIM;                 // [32][D] bf16 (col C = 1.0)
    float* partial = (float*)(Rt + (size_t)32 * D);    // [SPLITS][N][32] f32

    float* echo  = (float*)d_out;
    float* inten = echo + (size_t)N * C;

    const int nb_nrm = (N + D + RPB - 1) / RPB;
    hipLaunchKernelGGL(prep_kernel, dim3(nb_nrm + D / 128), dim3(256), 0, stream,
                       feat, exf, reps, Fn, Rt, N, N + D, D, C, nb_nrm);

    const int Dchunk = D / SPLITS;
    hipLaunchKernelGGL(fused_kernel, dim3(SPLITS, N / MT), dim3(256), 0, stream,
                       Fn, En, Rt, p, partial, N, D, C, Dchunk);

    hipLaunchKernelGGL(reduce_kernel, dim3(N * 32 / 256), dim3(256), 0, stream,
                       partial, echo, inten, N, SPLITS, C);
}

// Round 9
// 143.007 us; speedup vs baseline: 1.1724x; 1.1724x over previous
//
#include <hip/hip_runtime.h>
#include <cstdint>

#define HDIM 256
#define MT   256      // feature rows per block (4 waves x 64 rows)
#define BDW  16       // En rows per WAVE-PRIVATE window (one MFMA A-tile)
#define SPLITS 32
#define RPB  16       // rows per prep block (4 per wave)

typedef short bf16x8 __attribute__((ext_vector_type(8)));
typedef short bf16x4 __attribute__((ext_vector_type(4)));
typedef float f32x4  __attribute__((ext_vector_type(4)));

typedef const __attribute__((address_space(1))) short as1_short;
typedef __attribute__((address_space(3))) short as3_short;

static __device__ __forceinline__ short f2bf(float x) {
    union { float f; uint32_t u; } v; v.f = x;
    uint32_t u = v.u;
    uint32_t r = (u + 0x7fffu + ((u >> 16) & 1u)) >> 16;
    return (short)r;
}

// ---- prep (single dispatch):
//  blocks [0, nb_nrm)          : L2-normalize feature/ex_feature rows -> bf16,
//                                stored with XOR-16B-chunk swizzle; 4 rows/wave
//  blocks [nb_nrm, nb_nrm+128) : transpose class reps to Rt[32][D] (col C = 1.0
//                                -> intensity falls out of the echo GEMM)
__global__ __launch_bounds__(256) void prep_kernel(const float* __restrict__ fsrc,
                                                   const float* __restrict__ esrc,
                                                   const float* __restrict__ reps,
                                                   short* __restrict__ dst,
                                                   short* __restrict__ rt,
                                                   int N, int rows_total,
                                                   int D, int C, int nb_nrm) {
    __shared__ float lds[128][29];                    // +1 pad col
    const int tid = threadIdx.x;
    if ((int)blockIdx.x < nb_nrm) {
        int wv = tid >> 6;
        int lane = tid & 63;
        int row0 = blockIdx.x * RPB + wv * 4;
        #pragma unroll
        for (int rr = 0; rr < 4; ++rr) {
            int row = row0 + rr;
            if (row >= rows_total) continue;
            const float* src = (row < N) ? (fsrc + (size_t)row * HDIM)
                                         : (esrc + (size_t)(row - N) * HDIM);
            const float4 v = *(const float4*)(src + lane * 4);
            float ss = v.x * v.x + v.y * v.y + v.z * v.z + v.w * v.w;
            #pragma unroll
            for (int m = 1; m < 64; m <<= 1) ss += __shfl_xor(ss, m, 64);
            float scale = 1.0f / fmaxf(sqrtf(ss), 1e-12f);
            short4 o;
            o.x = f2bf(v.x * scale); o.y = f2bf(v.y * scale);
            o.z = f2bf(v.z * scale); o.w = f2bf(v.w * scale);
            int chunk = (lane >> 1) ^ (row & 7);      // swizzled 16B-chunk index
            *(short4*)(dst + (size_t)row * HDIM + chunk * 8 + (lane & 1) * 4) = o;
        }
    } else {
        const int bx = blockIdx.x - nb_nrm;           // 0..127
        const int d0 = bx * 128;
        const int total = 128 * C;
        const float* src = reps + (size_t)d0 * C;
        for (int i = tid; i < total; i += 256)
            lds[i / C][i % C] = src[i];               // coalesced load
        __syncthreads();
        const int c = tid >> 3;                       // 0..31
        const int dsub = (tid & 7) * 16;              // 16 d per thread
        short* dstp = rt + (size_t)c * D + d0 + dsub;
        #pragma unroll
        for (int j0 = 0; j0 < 16; j0 += 4) {
            short4 o;
            float v0, v1, v2, v3;
            if (c < C) {
                v0 = lds[dsub + j0 + 0][c]; v1 = lds[dsub + j0 + 1][c];
                v2 = lds[dsub + j0 + 2][c]; v3 = lds[dsub + j0 + 3][c];
            } else {
                float f = (c == C) ? 1.0f : 0.0f;     // ones column -> intensity
                v0 = v1 = v2 = v3 = f;
            }
            o.x = f2bf(v0); o.y = f2bf(v1); o.z = f2bf(v2); o.w = f2bf(v3);
            *(short4*)(dstp + j0) = o;                // coalesced store
        }
    }
}

// ---- fused: GEMM1 computes S^T via operand-swapped MFMA (A=En, B=Fn); the
// activated tile sits in 16x16x16 B-operand layout and feeds GEMM2
// echo^T += Rt_frag * a^T with NO LDS round-trip.
//
// SESSION LEDGER:
//  r9/r10/r16: intra-wave pipelining via extra live regs -> spill at every
//              budget (128 and 256 caps). DEAD permanently.
//  r11 no-LDS direct-global  -> VMEM issue-bound (16 lines/load). DEAD.
//  r13 atomic epilogue       -> cross-XCD fabric traffic. DEAD.
//  r14 MT=256 @(256,2)       -> LDS/FETCH halved, wall flat: ~40% of window
//                               is dependency stall under barrier lockstep.
//  r17 barrier-free v1       -> NaN: STAGE_W stride bug (i*1024 shorts =
//      2048B, but one gload_lds(16B) covers 64x16B = 1024B = 512 shorts) ->
//      half the window never staged + OOB writes into neighbor wave's buffer.
//  r18 = r17 with stride fixed to i*512 -> INFRA FAILURE (container died
//      twice, never ran). Resubmitting unchanged.
// Design: BARRIER-FREE WAVE-PRIVATE STAGING. Each wave reads the whole En
// tile anyway at MT=256, so cooperative staging (the only reason for
// __syncthreads) is replaced by per-wave 16-row double-buffered windows:
// 4 waves x 2 x 8KB = 64KB/block. Zero inter-wave communication -> no
// barriers; stage(it) landing guaranteed by counted s_waitcnt vmcnt(8):
// ops newer than stage(it) = stage(it+1)[8] (+ rt[2] in steady state),
// completions in-order -> wait is non-draining. 8 waves/CU drift freely:
// one wave's act VALU overlaps another's MFMA/ds_read on the same SIMD
// (m114 co-issue). Register-neutral vs r14. Rule-18: every asm waitcnt is
// volatile+"memory" followed by sched_barrier(0); buffer overwrite fenced
// by lgkmcnt(0) (free: the 8 ds_reads were already consumed by GEMM1's
// MFMAs); last window peeled with vmcnt(0).
__global__ __launch_bounds__(256, 2) void fused_kernel(const short* __restrict__ Fn,
                                                       const short* __restrict__ En,
                                                       const short* __restrict__ Rt,
                                                       const int* __restrict__ pptr,
                                                       float* __restrict__ partial,
                                                       int N, int D, int C, int Dchunk) {
    __shared__ __align__(16) short lds_en[4][2][BDW * HDIM];   // per-wave dbuf, 64 KB

    const int tid  = threadIdx.x;
    const int lane = tid & 63;
    const int wv   = tid >> 6;
    const int q    = lane >> 4;
    const int l    = lane & 15;
    const int p    = pptr[0];

    const int Mbase = blockIdx.y * MT;
    const int dbase = blockIdx.x * Dchunk;

    const f32x4 zf = {0.0f, 0.0f, 0.0f, 0.0f};

    // Fn fragments (B-operand of GEMM1): B[k=ks*32+q*8+j][n=l] — de-swizzle in
    // the address. 4 f-tiles x 8 ks = 128 VGPR, resident for the whole kernel.
    bf16x8 afrag[4][8];
    #pragma unroll
    for (int fn = 0; fn < 4; ++fn) {
        const short* rowp = Fn + (size_t)(Mbase + wv * 64 + fn * 16 + l) * HDIM;
        #pragma unroll
        for (int ks = 0; ks < 8; ++ks)
            afrag[fn][ks] = *(const bf16x8*)(rowp + (((ks * 4 + q) ^ (l & 7)) << 3));
    }

    // echo^T accumulators: [f-tile][c-tile], C/D layout col=f(l), row=c(q*4+r)
    f32x4 echo_acc[4][2];
    #pragma unroll
    for (int fn = 0; fn < 4; ++fn) { echo_acc[fn][0] = zf; echo_acc[fn][1] = zf; }

    const int nwin = Dchunk / BDW;       // 32 wave-private windows

    // Wave-private stage: window it_ (16 En rows = 8KB) -> lds_en[wv][buf_].
    // One gload_lds(16B) covers 64 lanes x 16B = 1024B = 512 shorts (r17 bug:
    // stride was 1024 shorts). LDS dest: wave-uniform base + lane*16B (HW);
    // global source per-lane. 8 instructions cover the full 8KB window.
    #define STAGE_W(buf_, it_)                                                      \
        {                                                                           \
            const short* gbase = En + (size_t)(dbase + (it_) * BDW) * HDIM + lane * 8;\
            as3_short* lbase = (as3_short*)(&lds_en[wv][buf_][0]);                  \
            _Pragma("unroll")                                                       \
            for (int i = 0; i < 8; ++i) {                                           \
                __builtin_amdgcn_global_load_lds((as1_short*)(gbase + i * 512),     \
                                                 lbase + i * 512, 16, 0, 0);        \
            }                                                                       \
        }

    const short* rtp = Rt + (size_t)l * D + q * 4;    // c-tile 0 row; +16*D for tile 1

    STAGE_W(0, 0)
    STAGE_W(1, 1)                        // 16 outstanding

    for (int it = 0; it < nwin; ++it) {
        const int buf = it & 1;

        // stage(it) landed: >=8 newer VMEM ops (stage(it+1) [+ rt of it-1])
        // outstanding -> vmcnt(8) drains exactly through stage(it).
        if (it < nwin - 1) {
            asm volatile("s_waitcnt vmcnt(8)" ::: "memory");
        } else {
            asm volatile("s_waitcnt vmcnt(0)" ::: "memory");   // peeled tail
        }
        __builtin_amdgcn_sched_barrier(0);

        const int d0 = dbase + it * BDW;

        // GEMM1: S^T tile 16(D) x 64(M), K=256, from the wave's own buffer.
        // row l in window; swizzle key (global row)&7 == l&7 (d0 multiple of 16).
        f32x4 sT[4];
        #pragma unroll
        for (int fn = 0; fn < 4; ++fn) sT[fn] = zf;
        #pragma unroll
        for (int ks = 0; ks < 8; ++ks) {
            const int slot = (ks * 4 + q) ^ (l & 7);
            bf16x8 ef = *(const bf16x8*)(&lds_en[wv][buf][l * HDIM + slot * 8]);
            #pragma unroll
            for (int fn = 0; fn < 4; ++fn)
                sT[fn] = __builtin_amdgcn_mfma_f32_16x16x32_bf16(ef, afrag[fn][ks], sT[fn], 0, 0, 0);
        }

        // all 8 ds_reads consumed by the MFMAs above -> lgkmcnt(0) is ~free;
        // it fences the buffer against the overwrite below.
        asm volatile("s_waitcnt lgkmcnt(0)" ::: "memory");
        __builtin_amdgcn_sched_barrier(0);
        if (it + 2 < nwin) STAGE_W(buf, it + 2)

        // activation in-register -> packed bf16x4 (16x16x16 B-layout)
        bf16x4 pfrag[4];
        #pragma unroll
        for (int fn = 0; fn < 4; ++fn) {
            bf16x4 pf;
            #pragma unroll
            for (int r = 0; r < 4; ++r) {
                float sv = sT[fn][r];
                float a;
                if (p == 3)      a = sv * sv * sv;
                else if (p == 1) a = sv;
                else if (p == 2) a = sv * fabsf(sv);
                else             a = copysignf(powf(fabsf(sv), (float)p), sv);
                pf[r] = f2bf(a);
            }
            pfrag[fn] = pf;
        }

        // GEMM2: echo^T += Rt_frag(A) * a^T(B), 16x16x16, K=16 (this window).
        // rt loads are VGPR loads: the compiler's waitcnt insertion counts the
        // newer stage ops and emits its own counted vmcnt before the use.
        bf16x4 rt0 = *(const bf16x4*)(rtp + d0);                  // c-tile 0
        bf16x4 rt1 = *(const bf16x4*)(rtp + (size_t)16 * D + d0); // c-tile 1
        #pragma unroll
        for (int fn = 0; fn < 4; ++fn) {
            echo_acc[fn][0] = __builtin_amdgcn_mfma_f32_16x16x16bf16_1k(rt0, pfrag[fn], echo_acc[fn][0], 0, 0, 0);
            echo_acc[fn][1] = __builtin_amdgcn_mfma_f32_16x16x16bf16_1k(rt1, pfrag[fn], echo_acc[fn][1], 0, 0, 0);
        }
    }

    // Epilogue: echo^T C-layout (col f = l, rows c = ct*16 + q*4 + r) -> one
    // float4 store per (f-tile, c-tile); reduce kernel ignores c > C.
    #pragma unroll
    for (int fn = 0; fn < 4; ++fn) {
        const int grow = Mbase + wv * 64 + fn * 16 + l;
        float* rowp = partial + ((size_t)blockIdx.x * N + grow) * 32 + q * 4;
        *(f32x4*)(rowp)      = echo_acc[fn][0];
        *(f32x4*)(rowp + 16) = echo_acc[fn][1];
    }

    #undef STAGE_W
}

// ---- reduce: sum partials over splits; col<C -> echo, col==C -> intensity ----
__global__ __launch_bounds__(256) void reduce_kernel(const float* __restrict__ partial,
                                                     float* __restrict__ echo,
                                                     float* __restrict__ inten,
                                                     int N, int splits, int C) {
    int t = blockIdx.x * 256 + threadIdx.x;    // N*32 threads
    int row = t >> 5, c = t & 31;
    if (row >= N || c > C) return;
    float s = 0.0f;
    for (int k = 0; k < splits; ++k)
        s += partial[((size_t)k * N + (size_t)row) * 32 + c];
    if (c < C) echo[(size_t)row * C + c] = s;
    else       inten[row] = s;
}

extern "C" void kernel_launch(void* const* d_in, const int* in_sizes, int n_in,
                              void* d_out, int out_size, void* d_ws, size_t ws_size,
                              hipStream_t stream) {
    const int N = in_sizes[0] / HDIM;       // 4096
    const int D = in_sizes[1] / HDIM;       // 16384
    const int C = in_sizes[2] / D;          // 28

    const float* feat = (const float*)d_in[0];
    const float* exf  = (const float*)d_in[1];
    const float* reps = (const float*)d_in[2];
    const int*   p    = (const int*)d_in[3];

    short* Fn = (short*)d_ws;                          // [N][256] bf16 (swizzled)
    short* En = Fn + (size_t)N * HDIM;                 // [D][256] bf16 (swizzled)
    short* Rt = En + (size_t)D * HDIM;                 // [32][D] bf16 (col C = 1.0)
    float* partial = (float*)(Rt + (size_t)32 * D);    // [SPLITS][N][32] f32

    float* echo  = (float*)d_out;
    float* inten = echo + (size_t)N * C;

    const int nb_nrm = (N + D + RPB - 1) / RPB;
    hipLaunchKernelGGL(prep_kernel, dim3(nb_nrm + D / 128), dim3(256), 0, stream,
                       feat, exf, reps, Fn, Rt, N, N + D, D, C, nb_nrm);

    const int Dchunk = D / SPLITS;
    hipLaunchKernelGGL(fused_kernel, dim3(SPLITS, N / MT), dim3(256), 0, stream,
                       Fn, En, Rt, p, partial, N, D, C, Dchunk);

    hipLaunchKernelGGL(reduce_kernel, dim3(N * 32 / 256), dim3(256), 0, stream,
                       partial, echo, inten, N, SPLITS, C);
}

// Round 10
// 141.166 us; speedup vs baseline: 1.1877x; 1.0130x over previous
//
#include <hip/hip_runtime.h>
#include <cstdint>

#define HDIM 256
#define MT   256      // feature rows per block (4 waves x 64 rows)
#define BDW  16       // En rows per WAVE-PRIVATE window (one MFMA A-tile)
#define SPLITS 32
#define RPB  16       // rows per prep block (4 per wave)

typedef short bf16x8 __attribute__((ext_vector_type(8)));
typedef short bf16x4 __attribute__((ext_vector_type(4)));
typedef float f32x4  __attribute__((ext_vector_type(4)));

typedef const __attribute__((address_space(1))) short as1_short;
typedef __attribute__((address_space(3))) short as3_short;

static __device__ __forceinline__ short f2bf(float x) {
    union { float f; uint32_t u; } v; v.f = x;
    uint32_t u = v.u;
    uint32_t r = (u + 0x7fffu + ((u >> 16) & 1u)) >> 16;
    return (short)r;
}

// ---- prep (single dispatch):
//  blocks [0, nb_nrm)          : L2-normalize feature/ex_feature rows -> bf16,
//                                stored with XOR-16B-chunk swizzle; 4 rows/wave
//  blocks [nb_nrm, nb_nrm+128) : transpose class reps to Rt[32][D] (col C = 1.0
//                                -> intensity falls out of the echo GEMM)
__global__ __launch_bounds__(256) void prep_kernel(const float* __restrict__ fsrc,
                                                   const float* __restrict__ esrc,
                                                   const float* __restrict__ reps,
                                                   short* __restrict__ dst,
                                                   short* __restrict__ rt,
                                                   int N, int rows_total,
                                                   int D, int C, int nb_nrm) {
    __shared__ float lds[128][29];                    // +1 pad col
    const int tid = threadIdx.x;
    if ((int)blockIdx.x < nb_nrm) {
        int wv = tid >> 6;
        int lane = tid & 63;
        int row0 = blockIdx.x * RPB + wv * 4;
        #pragma unroll
        for (int rr = 0; rr < 4; ++rr) {
            int row = row0 + rr;
            if (row >= rows_total) continue;
            const float* src = (row < N) ? (fsrc + (size_t)row * HDIM)
                                         : (esrc + (size_t)(row - N) * HDIM);
            const float4 v = *(const float4*)(src + lane * 4);
            float ss = v.x * v.x + v.y * v.y + v.z * v.z + v.w * v.w;
            #pragma unroll
            for (int m = 1; m < 64; m <<= 1) ss += __shfl_xor(ss, m, 64);
            float scale = 1.0f / fmaxf(sqrtf(ss), 1e-12f);
            short4 o;
            o.x = f2bf(v.x * scale); o.y = f2bf(v.y * scale);
            o.z = f2bf(v.z * scale); o.w = f2bf(v.w * scale);
            int chunk = (lane >> 1) ^ (row & 7);      // swizzled 16B-chunk index
            *(short4*)(dst + (size_t)row * HDIM + chunk * 8 + (lane & 1) * 4) = o;
        }
    } else {
        const int bx = blockIdx.x - nb_nrm;           // 0..127
        const int d0 = bx * 128;
        const int total = 128 * C;
        const float* src = reps + (size_t)d0 * C;
        for (int i = tid; i < total; i += 256)
            lds[i / C][i % C] = src[i];               // coalesced load
        __syncthreads();
        const int c = tid >> 3;                       // 0..31
        const int dsub = (tid & 7) * 16;              // 16 d per thread
        short* dstp = rt + (size_t)c * D + d0 + dsub;
        #pragma unroll
        for (int j0 = 0; j0 < 16; j0 += 4) {
            short4 o;
            float v0, v1, v2, v3;
            if (c < C) {
                v0 = lds[dsub + j0 + 0][c]; v1 = lds[dsub + j0 + 1][c];
                v2 = lds[dsub + j0 + 2][c]; v3 = lds[dsub + j0 + 3][c];
            } else {
                float f = (c == C) ? 1.0f : 0.0f;     // ones column -> intensity
                v0 = v1 = v2 = v3 = f;
            }
            o.x = f2bf(v0); o.y = f2bf(v1); o.z = f2bf(v2); o.w = f2bf(v3);
            *(short4*)(dstp + j0) = o;                // coalesced store
        }
    }
}

// ---- fused: GEMM1 computes S^T via operand-swapped MFMA (A=En, B=Fn); the
// activated tile sits in 16x16x16 B-operand layout and feeds GEMM2
// echo^T += Rt_frag * a^T with NO LDS round-trip.
//
// SESSION LEDGER:
//  r9/r10/r16: intra-wave pipelining via extra live regs -> spill. DEAD.
//  r11 no-LDS direct-global  -> VMEM issue-bound (16 lines/load). DEAD.
//  r13 atomic epilogue       -> cross-XCD fabric traffic. DEAD.
//  r14 MT=256 @(256,2)       -> traffic halved, wall flat.
//  r18 barrier-free staging  -> PASSED, wall flat (72.5us): r8(16w,bar),
//      r14(8w,bar), r18(8w,nobar) all ~70us, all pipes <=25%. Wall invariant
//      to occupancy AND barriers -> one shared serializer.
// r19 DIAGNOSIS: the per-window Rt loads were issued (program order) AFTER
// the next-tile STAGE. GEMM2's use of rt forces the compiler to wait for the
// NEWEST VMEM ops -> s_waitcnt vmcnt(0) -> drains the whole gload_lds queue
// EVERY WINDOW, every wave. This is m97's barrier-drain mechanism repeated
// per window via the compiler's automatic wait. Retrodicts the entire
// plateau: r10's VALU cut, r14's traffic cut, r18's barrier cut all flat
// because this drain dominated throughout.
// r19 FIX: issue rt loads between GEMM1 and STAGE (pinned above STAGE by the
// existing sched_barrier(0)). GEMM2's wait becomes counted vmcnt(8) —
// non-draining; rt's L2 latency hides under the act VALU. Staging now truly
// pipelines 2-deep. +4 VGPR only.
__global__ __launch_bounds__(256, 2) void fused_kernel(const short* __restrict__ Fn,
                                                       const short* __restrict__ En,
                                                       const short* __restrict__ Rt,
                                                       const int* __restrict__ pptr,
                                                       float* __restrict__ partial,
                                                       int N, int D, int C, int Dchunk) {
    __shared__ __align__(16) short lds_en[4][2][BDW * HDIM];   // per-wave dbuf, 64 KB

    const int tid  = threadIdx.x;
    const int lane = tid & 63;
    const int wv   = tid >> 6;
    const int q    = lane >> 4;
    const int l    = lane & 15;
    const int p    = pptr[0];

    const int Mbase = blockIdx.y * MT;
    const int dbase = blockIdx.x * Dchunk;

    const f32x4 zf = {0.0f, 0.0f, 0.0f, 0.0f};

    // Fn fragments (B-operand of GEMM1): B[k=ks*32+q*8+j][n=l] — de-swizzle in
    // the address. 4 f-tiles x 8 ks = 128 VGPR, resident for the whole kernel.
    bf16x8 afrag[4][8];
    #pragma unroll
    for (int fn = 0; fn < 4; ++fn) {
        const short* rowp = Fn + (size_t)(Mbase + wv * 64 + fn * 16 + l) * HDIM;
        #pragma unroll
        for (int ks = 0; ks < 8; ++ks)
            afrag[fn][ks] = *(const bf16x8*)(rowp + (((ks * 4 + q) ^ (l & 7)) << 3));
    }

    // echo^T accumulators: [f-tile][c-tile], C/D layout col=f(l), row=c(q*4+r)
    f32x4 echo_acc[4][2];
    #pragma unroll
    for (int fn = 0; fn < 4; ++fn) { echo_acc[fn][0] = zf; echo_acc[fn][1] = zf; }

    const int nwin = Dchunk / BDW;       // 32 wave-private windows

    // Wave-private stage: window it_ (16 En rows = 8KB) -> lds_en[wv][buf_].
    // One gload_lds(16B) covers 64 lanes x 16B = 1024B = 512 shorts.
    #define STAGE_W(buf_, it_)                                                      \
        {                                                                           \
            const short* gbase = En + (size_t)(dbase + (it_) * BDW) * HDIM + lane * 8;\
            as3_short* lbase = (as3_short*)(&lds_en[wv][buf_][0]);                  \
            _Pragma("unroll")                                                       \
            for (int i = 0; i < 8; ++i) {                                           \
                __builtin_amdgcn_global_load_lds((as1_short*)(gbase + i * 512),     \
                                                 lbase + i * 512, 16, 0, 0);        \
            }                                                                       \
        }

    const short* rtp = Rt + (size_t)l * D + q * 4;    // c-tile 0 row; +16*D for tile 1

    STAGE_W(0, 0)
    STAGE_W(1, 1)                        // 16 outstanding

    for (int it = 0; it < nwin; ++it) {
        const int buf = it & 1;

        // stage(it) landed: >=8 newer VMEM ops outstanding (stage(it+1)) ->
        // vmcnt(8) drains exactly through stage(it) without idling the queue.
        if (it < nwin - 1) {
            asm volatile("s_waitcnt vmcnt(8)" ::: "memory");
        } else {
            asm volatile("s_waitcnt vmcnt(0)" ::: "memory");   // peeled tail
        }
        __builtin_amdgcn_sched_barrier(0);

        const int d0 = dbase + it * BDW;

        // GEMM1: S^T tile 16(D) x 64(M), K=256, from the wave's own buffer.
        f32x4 sT[4];
        #pragma unroll
        for (int fn = 0; fn < 4; ++fn) sT[fn] = zf;
        #pragma unroll
        for (int ks = 0; ks < 8; ++ks) {
            const int slot = (ks * 4 + q) ^ (l & 7);
            bf16x8 ef = *(const bf16x8*)(&lds_en[wv][buf][l * HDIM + slot * 8]);
            #pragma unroll
            for (int fn = 0; fn < 4; ++fn)
                sT[fn] = __builtin_amdgcn_mfma_f32_16x16x32_bf16(ef, afrag[fn][ks], sT[fn], 0, 0, 0);
        }

        // r19 FIX: Rt loads issued HERE — before the STAGE in program order
        // (the sched_barrier below pins them above it). GEMM2's wait for rt
        // is then counted vmcnt(8) (8 stage ops newer), NOT a vmcnt(0) drain;
        // rt's L2 latency hides under the activation VALU.
        bf16x4 rt0 = *(const bf16x4*)(rtp + d0);                  // c-tile 0
        bf16x4 rt1 = *(const bf16x4*)(rtp + (size_t)16 * D + d0); // c-tile 1

        // all 8 ds_reads consumed by the MFMAs above -> lgkmcnt(0) is ~free;
        // it fences the buffer against the overwrite below.
        asm volatile("s_waitcnt lgkmcnt(0)" ::: "memory");
        __builtin_amdgcn_sched_barrier(0);
        if (it + 2 < nwin) STAGE_W(buf, it + 2)

        // activation in-register -> packed bf16x4 (16x16x16 B-layout)
        bf16x4 pfrag[4];
        #pragma unroll
        for (int fn = 0; fn < 4; ++fn) {
            bf16x4 pf;
            #pragma unroll
            for (int r = 0; r < 4; ++r) {
                float sv = sT[fn][r];
                float a;
                if (p == 3)      a = sv * sv * sv;
                else if (p == 1) a = sv;
                else if (p == 2) a = sv * fabsf(sv);
                else             a = copysignf(powf(fabsf(sv), (float)p), sv);
                pf[r] = f2bf(a);
            }
            pfrag[fn] = pf;
        }

        // GEMM2: echo^T += Rt_frag(A) * a^T(B), 16x16x16, K=16 (this window)
        #pragma unroll
        for (int fn = 0; fn < 4; ++fn) {
            echo_acc[fn][0] = __builtin_amdgcn_mfma_f32_16x16x16bf16_1k(rt0, pfrag[fn], echo_acc[fn][0], 0, 0, 0);
            echo_acc[fn][1] = __builtin_amdgcn_mfma_f32_16x16x16bf16_1k(rt1, pfrag[fn], echo_acc[fn][1], 0, 0, 0);
        }
    }

    // Epilogue: echo^T C-layout (col f = l, rows c = ct*16 + q*4 + r) -> one
    // float4 store per (f-tile, c-tile); reduce kernel ignores c > C.
    #pragma unroll
    for (int fn = 0; fn < 4; ++fn) {
        const int grow = Mbase + wv * 64 + fn * 16 + l;
        float* rowp = partial + ((size_t)blockIdx.x * N + grow) * 32 + q * 4;
        *(f32x4*)(rowp)      = echo_acc[fn][0];
        *(f32x4*)(rowp + 16) = echo_acc[fn][1];
    }

    #undef STAGE_W
}

// ---- reduce: sum partials over splits; col<C -> echo, col==C -> intensity ----
__global__ __launch_bounds__(256) void reduce_kernel(const float* __restrict__ partial,
                                                     float* __restrict__ echo,
                                                     float* __restrict__ inten,
                                                     int N, int splits, int C) {
    int t = blockIdx.x * 256 + threadIdx.x;    // N*32 threads
    int row = t >> 5, c = t & 31;
    if (row >= N || c > C) return;
    float s = 0.0f;
    for (int k = 0; k < splits; ++k)
        s += partial[((size_t)k * N + (size_t)row) * 32 + c];
    if (c < C) echo[(size_t)row * C + c] = s;
    else       inten[row] = s;
}

extern "C" void kernel_launch(void* const* d_in, const int* in_sizes, int n_in,
                              void* d_out, int out_size, void* d_ws, size_t ws_size,
                              hipStream_t stream) {
    const int N = in_sizes[0] / HDIM;       // 4096
    const int D = in_sizes[1] / HDIM;       // 16384
    const int C = in_sizes[2] / D;          // 28

    const float* feat = (const float*)d_in[0];
    const float* exf  = (const float*)d_in[1];
    const float* reps = (const float*)d_in[2];
    const int*   p    = (const int*)d_in[3];

    short* Fn = (short*)d_ws;                          // [N][256] bf16 (swizzled)
    short* En = Fn + (size_t)N * HDIM;                 // [D][256] bf16 (swizzled)
    short* Rt = En + (size_t)D * HDIM;                 // [32][D] bf16 (col C = 1.0)
    float* partial = (float*)(Rt + (size_t)32 * D);    // [SPLITS][N][32] f32

    float* echo  = (float*)d_out;
    float* inten = echo + (size_t)N * C;

    const int nb_nrm = (N + D + RPB - 1) / RPB;
    hipLaunchKernelGGL(prep_kernel, dim3(nb_nrm + D / 128), dim3(256), 0, stream,
                       feat, exf, reps, Fn, Rt, N, N + D, D, C, nb_nrm);

    const int Dchunk = D / SPLITS;
    hipLaunchKernelGGL(fused_kernel, dim3(SPLITS, N / MT), dim3(256), 0, stream,
                       Fn, En, Rt, p, partial, N, D, C, Dchunk);

    hipLaunchKernelGGL(reduce_kernel, dim3(N * 32 / 256), dim3(256), 0, stream,
                       partial, echo, inten, N, SPLITS, C);
}